// Round 11
// baseline (100.116 us; speedup 1.0000x reference)
//
#include <hip/hip_runtime.h>
#include <hip/hip_bf16.h>
#include <math.h>

#define NROWS 4096
#define DDIM  512
#define INV_TAU 1.25f

typedef __attribute__((ext_vector_type(8))) short short8;
typedef __attribute__((ext_vector_type(4))) float f32x4;

__device__ inline void gload_lds16(const void* g, void* l) {
  __builtin_amdgcn_global_load_lds(
      (const __attribute__((address_space(1))) void*)g,
      (__attribute__((address_space(3))) void*)l, 16, 0, 0);
}

__device__ inline unsigned short f2bf(float f) {
  __hip_bfloat16 h = __float2bfloat16(f);
  return __builtin_bit_cast(unsigned short, h);
}
__device__ inline float bf2f(unsigned short u) {
  return __bfloat162float(__builtin_bit_cast(__hip_bfloat16, u));
}

// fp8 e4m3 (positive range only: s in [0.28, 3.6], all normal; proven R7/R8)
__device__ inline unsigned f2e4m3(float s) {
  unsigned b = __builtin_bit_cast(unsigned, s);
  return (b + 0x80000u - 0x3C000000u) >> 20;
}
__device__ inline float e4m32f(unsigned u8) {
  return __builtin_bit_cast(float, (u8 << 20) + 0x3C000000u);
}

// ---------------------------------------------------------------------------
// Kernel 1: f32 -> bf16 conversion for v1, v2, W ; zero the nsq accumulators.
// ---------------------------------------------------------------------------
__global__ void convert_kernel(const float* __restrict__ v1,
                               const float* __restrict__ v2,
                               const float* __restrict__ W,
                               unsigned short* __restrict__ v1b,
                               unsigned short* __restrict__ v2b,
                               unsigned short* __restrict__ Wb,
                               float* __restrict__ nsq1,
                               float* __restrict__ nsq2) {
  int idx = blockIdx.x * blockDim.x + threadIdx.x;
  if (idx < NROWS) { nsq1[idx] = 0.f; nsq2[idx] = 0.f; }
  const int TOTV = (NROWS * DDIM) / 4;
  const int TOTW = (DDIM * DDIM) / 4;
  const int total = 2 * TOTV + TOTW;
  const int stride = gridDim.x * blockDim.x;
  for (int i = idx; i < total; i += stride) {
    const float4* src; unsigned short* dst; int j;
    if (i < TOTV)            { src = (const float4*)v1; dst = v1b; j = i; }
    else if (i < 2 * TOTV)   { src = (const float4*)v2; dst = v2b; j = i - TOTV; }
    else                     { src = (const float4*)W;  dst = Wb;  j = i - 2 * TOTV; }
    float4 x = src[j];
    ushort4 o;
    o.x = f2bf(x.x); o.y = f2bf(x.y); o.z = f2bf(x.z); o.w = f2bf(x.w);
    *(ushort4*)&dst[j * 4] = o;
  }
}

// ---------------------------------------------------------------------------
// Kernel 2: projection GEMM  z = elu(v @ W^T + b), bf16 out, + row sum(z^2).
// ---------------------------------------------------------------------------
__global__ __launch_bounds__(256) void proj_kernel(
    const unsigned short* __restrict__ v1b, const unsigned short* __restrict__ v2b,
    const unsigned short* __restrict__ Wb,  const float* __restrict__ bias,
    unsigned short* __restrict__ z1b, unsigned short* __restrict__ z2b,
    float* __restrict__ nsq1, float* __restrict__ nsq2) {
  __shared__ __align__(16) unsigned short As[128 * 32];
  __shared__ __align__(16) unsigned short Bs[128 * 32];
  const int tid = threadIdx.x;
  const int wid = tid >> 6, lane = tid & 63;
  const int wm = wid >> 1, wn = wid & 1;
  const int l15 = lane & 15, l4 = lane >> 4;

  const int zsel = blockIdx.z;
  const unsigned short* Ag = (zsel ? v2b : v1b) + (size_t)blockIdx.y * 128 * DDIM;
  const unsigned short* Bg = Wb + (size_t)blockIdx.x * 128 * DDIM;
  unsigned short* Z = (zsel ? z2b : z1b);
  float* nsq = (zsel ? nsq2 : nsq1);

  f32x4 acc[4][4];
#pragma unroll
  for (int m = 0; m < 4; ++m)
#pragma unroll
    for (int n = 0; n < 4; ++n) acc[m][n] = (f32x4){0.f, 0.f, 0.f, 0.f};

  for (int kt = 0; kt < DDIM; kt += 32) {
#pragma unroll
    for (int i = 0; i < 2; ++i) {
      int off = i * 4096 + tid * 16;
      int row = off >> 6;
      int kb  = off & 63;
      gload_lds16((const char*)(Ag + row * DDIM + kt) + kb,
                  (char*)As + i * 4096 + wid * 1024);
      gload_lds16((const char*)(Bg + row * DDIM + kt) + kb,
                  (char*)Bs + i * 4096 + wid * 1024);
    }
    asm volatile("s_waitcnt vmcnt(0)" ::: "memory");
    __syncthreads();
    short8 av[4], bv[4];
#pragma unroll
    for (int m = 0; m < 4; ++m)
      av[m] = *(const short8*)&As[(wm * 64 + m * 16 + l15) * 32 + l4 * 8];
#pragma unroll
    for (int n = 0; n < 4; ++n)
      bv[n] = *(const short8*)&Bs[(wn * 64 + n * 16 + l15) * 32 + l4 * 8];
#pragma unroll
    for (int m = 0; m < 4; ++m)
#pragma unroll
      for (int n = 0; n < 4; ++n)
        acc[m][n] = __builtin_amdgcn_mfma_f32_16x16x32_bf16(
            av[m], bv[n], acc[m][n], 0, 0, 0);
    __syncthreads();
  }

  const int rowBase = blockIdx.y * 128 + wm * 64;
  const int colBase = blockIdx.x * 128 + wn * 64;
  float bcol[4];
#pragma unroll
  for (int n = 0; n < 4; ++n) bcol[n] = bias[colBase + n * 16 + l15];
#pragma unroll
  for (int m = 0; m < 4; ++m) {
#pragma unroll
    for (int reg = 0; reg < 4; ++reg) {
      int gRow = rowBase + m * 16 + l4 * 4 + reg;
      float rs = 0.f;
#pragma unroll
      for (int n = 0; n < 4; ++n) {
        int gCol = colBase + n * 16 + l15;
        float y = acc[m][n][reg] + bcol[n];
        float zv = (y > 0.f) ? y : expm1f(y);
        unsigned short zb = f2bf(zv);
        Z[(size_t)gRow * DDIM + gCol] = zb;
        float zf = bf2f(zb);
        rs += zf * zf;
      }
      rs += __shfl_xor(rs, 1, 64);
      rs += __shfl_xor(rs, 2, 64);
      rs += __shfl_xor(rs, 4, 64);
      rs += __shfl_xor(rs, 8, 64);
      if (l15 == 0) atomicAdd(&nsq[gRow], rs);
    }
  }
}

// ---------------------------------------------------------------------------
// Kernel 3: fused 2-tile chain.  Per block: K-loop(A); convert accA->fp8 sCh;
// K-loop(B) with tile-A pos/neg stream interleaved per K-step (counted vmcnt);
// convert accB->sCh; stream tile B.  grid: 512  block: 256.
// ---------------------------------------------------------------------------
__global__ __launch_bounds__(256, 3) void dots_kernel(
    const unsigned short* __restrict__ z1b, const unsigned short* __restrict__ z2b,
    const float* __restrict__ nsq1, const float* __restrict__ nsq2,
    const float* __restrict__ pos, const float* __restrict__ neg,
    double* __restrict__ partials) {
  __shared__ __align__(16) char smem[2][16384];       // GEMM staging (2 buf)
  __shared__ __align__(16) unsigned char sCh[16384];  // fp8 s-tile [128][128]
  __shared__ float redP[4], redG[4];

  const int tid = threadIdx.x;
  const int wid = tid >> 6, lane = tid & 63;
  const int wm = wid >> 1, wn = wid & 1;
  const int l15 = lane & 15, l4 = lane >> 4;
  const int l31 = lane & 31, lh = lane >> 5;

  const int bid = blockIdx.x;
  const int by = bid >> 4;
  const int bxA = (bid & 15) * 2, bxB = bxA + 1;
  const int blockRow = by * 128;

  const unsigned short* Ag  = z1b + (size_t)by * 128 * DDIM;
  const unsigned short* BgA = z2b + (size_t)bxA * 128 * DDIM;
  const unsigned short* BgB = z2b + (size_t)bxB * 128 * DDIM;

  // hoisted inverse norms
  float rs1v[4][4];
#pragma unroll
  for (int m = 0; m < 4; ++m)
#pragma unroll
    for (int reg = 0; reg < 4; ++reg)
      rs1v[m][reg] = rsqrtf(nsq1[blockRow + wm * 64 + m * 16 + l4 * 4 + reg]);
  float rs2A[4], rs2B[4];
#pragma unroll
  for (int n = 0; n < 4; ++n) {
    rs2A[n] = rsqrtf(nsq2[bxA * 128 + wn * 64 + n * 16 + l15]);
    rs2B[n] = rsqrtf(nsq2[bxB * 128 + wn * 64 + n * 16 + l15]);
  }

  // stream geometry: chunk c -> row srow0 + c*2 (tile-local), cols scol..+3
  const int srow0 = wid * 32 + lh;
  const int scol  = l31 * 4;
  const int aswz = (l4 ^ ((l15 >> 1) & 3)) * 8;

  f32x4 acc[4][4];
#pragma unroll
  for (int m = 0; m < 4; ++m)
#pragma unroll
    for (int n = 0; n < 4; ++n) acc[m][n] = (f32x4){0.f, 0.f, 0.f, 0.f};

#define STAGE(Bg, buf, t)                                                      \
  {                                                                            \
    _Pragma("unroll")                                                          \
    for (int i = 0; i < 2; ++i) {                                              \
      int off = i * 4096 + tid * 16;                                           \
      int row = off >> 6;                                                      \
      int gsw = ((off >> 4) & 3) ^ ((row >> 1) & 3);                           \
      gload_lds16((const char*)Ag + row * 1024 + (t) * 64 + gsw * 16,          \
                  smem[buf] + i * 4096 + wid * 1024);                          \
      gload_lds16((const char*)(Bg) + row * 1024 + (t) * 64 + gsw * 16,        \
                  smem[buf] + 8192 + i * 4096 + wid * 1024);                   \
    }                                                                          \
  }

#define FRAGS_MFMA(buf)                                                        \
  {                                                                            \
    const unsigned short* As = (const unsigned short*)smem[buf];               \
    const unsigned short* Bs = (const unsigned short*)(smem[buf] + 8192);      \
    short8 av[4], bv[4];                                                       \
    _Pragma("unroll")                                                          \
    for (int m = 0; m < 4; ++m)                                                \
      av[m] = *(const short8*)&As[(wm * 64 + m * 16 + l15) * 32 + aswz];       \
    _Pragma("unroll")                                                          \
    for (int n = 0; n < 4; ++n)                                                \
      bv[n] = *(const short8*)&Bs[(wn * 64 + n * 16 + l15) * 32 + aswz];       \
    _Pragma("unroll")                                                          \
    for (int m = 0; m < 4; ++m)                                                \
      _Pragma("unroll")                                                        \
      for (int n = 0; n < 4; ++n)                                              \
        acc[m][n] = __builtin_amdgcn_mfma_f32_16x16x32_bf16(                   \
            av[m], bv[n], acc[m][n], 0, 0, 0);                                 \
  }

#define CONVERT(rs2)                                                           \
  {                                                                            \
    _Pragma("unroll")                                                          \
    for (int m = 0; m < 4; ++m)                                                \
      _Pragma("unroll")                                                        \
      for (int reg = 0; reg < 4; ++reg) {                                      \
        int row = wm * 64 + m * 16 + l4 * 4 + reg;                             \
        _Pragma("unroll")                                                      \
        for (int n = 0; n < 4; ++n) {                                          \
          float s = __expf(acc[m][n][reg] * (rs1v[m][reg] * (rs2)[n]) * INV_TAU);\
          sCh[row * 128 + wn * 64 + n * 16 + l15] = (unsigned char)f2e4m3(s);  \
        }                                                                      \
        acc[m][0][reg] = 0.f; /* re-zero lazily below */                       \
      }                                                                        \
  }

#define SDECODE_FMA(sb, p, g)                                                  \
  {                                                                            \
    float s0 = e4m32f((sb) & 0x7Fu), s1 = e4m32f(((sb) >> 8) & 0x7Fu);         \
    float s2 = e4m32f(((sb) >> 16) & 0x7Fu), s3 = e4m32f(((sb) >> 24) & 0x7Fu);\
    sumP += s0 * (p)[0] + s1 * (p)[1] + s2 * (p)[2] + s3 * (p)[3];             \
    sumG += s0 * (g)[0] + s1 * (g)[1] + s2 * (g)[2] + s3 * (g)[3];             \
  }

  // ---------------- Phase 1: K-loop tile A ----------------
  STAGE(BgA, 0, 0);
  STAGE(BgA, 1, 1);
#pragma unroll
  for (int t = 0; t < 16; ++t) {
    if (t < 15) asm volatile("s_waitcnt vmcnt(4)" ::: "memory");
    else        asm volatile("s_waitcnt vmcnt(0)" ::: "memory");
    __builtin_amdgcn_s_barrier();
    FRAGS_MFMA(t & 1);
    __builtin_amdgcn_s_barrier();
    if (t < 14) STAGE(BgA, t & 1, t + 2);
  }

  // ---------------- Joint 1: prologue B + convert accA ----------------
  STAGE(BgB, 0, 0);
  STAGE(BgB, 1, 1);
  __builtin_amdgcn_sched_barrier(0);
  CONVERT(rs2A);
#pragma unroll
  for (int m = 0; m < 4; ++m)
#pragma unroll
    for (int n = 0; n < 4; ++n) acc[m][n] = (f32x4){0.f, 0.f, 0.f, 0.f};
  asm volatile("s_waitcnt lgkmcnt(0)" ::: "memory");
  __builtin_amdgcn_s_barrier();

  // ---------------- Phase 2: K-loop tile B + stream tile A ----------------
  const float* posA = pos + (size_t)(blockRow + srow0) * NROWS + bxA * 128 + scol;
  const float* negA = neg + (size_t)(blockRow + srow0) * NROWS + bxA * 128 + scol;
  f32x4 pv0, pv1, gv0, gv1;
  float sumP = 0.f, sumG = 0.f;
#pragma unroll
  for (int t = 0; t < 16; ++t) {
    if (t == 0)      asm volatile("s_waitcnt vmcnt(4)" ::: "memory");
    else if (t < 15) asm volatile("s_waitcnt vmcnt(6)" ::: "memory");
    else             asm volatile("s_waitcnt vmcnt(2)" ::: "memory");
    __builtin_amdgcn_s_barrier();
    unsigned sb = 0;
    if (t >= 2) sb = *(const unsigned*)&sCh[(srow0 + (t - 2) * 2) * 128 + scol];
    FRAGS_MFMA(t & 1);
    if (t >= 2) {
      if ((t & 1) == 0) { SDECODE_FMA(sb, pv0, gv0); }
      else              { SDECODE_FMA(sb, pv1, gv1); }
    }
    __builtin_amdgcn_s_barrier();
    if (t < 14) STAGE(BgB, t & 1, t + 2);
    __builtin_amdgcn_sched_barrier(0);
    {
      const float* pp = posA + (size_t)(t * 2) * NROWS;
      const float* gg = negA + (size_t)(t * 2) * NROWS;
      if ((t & 1) == 0) { pv0 = *(const f32x4*)pp; gv0 = *(const f32x4*)gg; }
      else              { pv1 = *(const f32x4*)pp; gv1 = *(const f32x4*)gg; }
    }
    __builtin_amdgcn_sched_barrier(0);
  }
  asm volatile("s_waitcnt vmcnt(0)" ::: "memory");
  {
    unsigned sb14 = *(const unsigned*)&sCh[(srow0 + 28) * 128 + scol];
    SDECODE_FMA(sb14, pv0, gv0);
    unsigned sb15 = *(const unsigned*)&sCh[(srow0 + 30) * 128 + scol];
    SDECODE_FMA(sb15, pv1, gv1);
  }

  // ---------------- Joint 2: convert accB ----------------
  __builtin_amdgcn_s_barrier();           // all sCh(A) reads done
  CONVERT(rs2B);
  asm volatile("s_waitcnt lgkmcnt(0)" ::: "memory");
  __builtin_amdgcn_s_barrier();

  // ---------------- Phase 3: stream tile B ----------------
  const float* posB = pos + (size_t)(blockRow + srow0) * NROWS + bxB * 128 + scol;
  const float* negB = neg + (size_t)(blockRow + srow0) * NROWS + bxB * 128 + scol;
  pv0 = *(const f32x4*)posB;                       gv0 = *(const f32x4*)negB;
  pv1 = *(const f32x4*)(posB + 2 * NROWS);         gv1 = *(const f32x4*)(negB + 2 * NROWS);
#pragma unroll
  for (int c = 0; c < 16; ++c) {
    unsigned sb = *(const unsigned*)&sCh[(srow0 + c * 2) * 128 + scol];
    if ((c & 1) == 0) {
      SDECODE_FMA(sb, pv0, gv0);
      if (c + 2 < 16) {
        pv0 = *(const f32x4*)(posB + (size_t)((c + 2) * 2) * NROWS);
        gv0 = *(const f32x4*)(negB + (size_t)((c + 2) * 2) * NROWS);
      }
    } else {
      SDECODE_FMA(sb, pv1, gv1);
      if (c + 2 < 16) {
        pv1 = *(const f32x4*)(posB + (size_t)((c + 2) * 2) * NROWS);
        gv1 = *(const f32x4*)(negB + (size_t)((c + 2) * 2) * NROWS);
      }
    }
  }

  // ---------------- reduction ----------------
#pragma unroll
  for (int sft = 1; sft < 64; sft <<= 1) {
    sumP += __shfl_xor(sumP, sft, 64);
    sumG += __shfl_xor(sumG, sft, 64);
  }
  if (lane == 0) { redP[wid] = sumP; redG[wid] = sumG; }
  __syncthreads();
  if (tid == 0) {
    double tp = (double)redP[0] + redP[1] + redP[2] + redP[3];
    double tg = (double)redG[0] + redG[1] + redG[2] + redG[3];
    partials[2 * bid]     = tp;
    partials[2 * bid + 1] = tp + tg;
  }
#undef STAGE
#undef FRAGS_MFMA
#undef CONVERT
#undef SDECODE_FMA
}

// ---------------------------------------------------------------------------
// Kernel 4: final reduce of n partial pairs -> -log(sumP / sumT)
// ---------------------------------------------------------------------------
__global__ void finalize_kernel(const double* __restrict__ partials, int n,
                                float* __restrict__ out) {
  __shared__ double sp[256], st[256];
  int t = threadIdx.x;
  double a = 0.0, b = 0.0;
  for (int i = t; i < n; i += 256) {
    a += partials[2 * i];
    b += partials[2 * i + 1];
  }
  sp[t] = a; st[t] = b;
  __syncthreads();
  for (int s = 128; s > 0; s >>= 1) {
    if (t < s) { sp[t] += sp[t + s]; st[t] += st[t + s]; }
    __syncthreads();
  }
  if (t == 0) out[0] = (float)(log(st[0]) - log(sp[0]));
}

// ---------------------------------------------------------------------------
extern "C" void kernel_launch(void* const* d_in, const int* in_sizes, int n_in,
                              void* d_out, int out_size, void* d_ws, size_t ws_size,
                              hipStream_t stream) {
  (void)in_sizes; (void)n_in; (void)out_size; (void)ws_size;
  const float* v1   = (const float*)d_in[0];
  const float* v2   = (const float*)d_in[1];
  const float* pos  = (const float*)d_in[2];
  const float* neg  = (const float*)d_in[3];
  const float* W    = (const float*)d_in[4];
  const float* bias = (const float*)d_in[5];

  char* ws = (char*)d_ws;
  unsigned short* z1b = (unsigned short*)(ws + 0);         // 4 MiB
  unsigned short* z2b = (unsigned short*)(ws + 4194304);   // 4 MiB
  float* nsq1         = (float*)(ws + 8388608);            // 16 KiB
  float* nsq2         = (float*)(ws + 8404992);            // 16 KiB
  double* partials    = (double*)(ws + 8421376);           // 8 KiB (512 pairs)
  unsigned short* v1b = (unsigned short*)(ws + 8486912);   // 4 MiB
  unsigned short* v2b = (unsigned short*)(ws + 12681216);  // 4 MiB
  unsigned short* Wb  = (unsigned short*)(ws + 16875520);  // 512 KiB
  float* out = (float*)d_out;

  hipLaunchKernelGGL(convert_kernel, dim3(1024), dim3(256), 0, stream,
                     v1, v2, W, v1b, v2b, Wb, nsq1, nsq2);
  hipLaunchKernelGGL(proj_kernel, dim3(DDIM / 128, NROWS / 128, 2), dim3(256), 0, stream,
                     v1b, v2b, Wb, bias, z1b, z2b, nsq1, nsq2);
  hipLaunchKernelGGL(dots_kernel, dim3(512), dim3(256), 0, stream,
                     z1b, z2b, nsq1, nsq2, pos, neg, partials);
  hipLaunchKernelGGL(finalize_kernel, dim3(1), dim3(256), 0, stream,
                     partials, 512, out);
}

// Round 12
// 99.437 us; speedup vs baseline: 1.0068x; 1.0068x over previous
//
#include <hip/hip_runtime.h>
#include <hip/hip_bf16.h>
#include <math.h>

#define NROWS 4096
#define DDIM  512
#define INV_TAU 1.25f

typedef __attribute__((ext_vector_type(8))) short short8;
typedef __attribute__((ext_vector_type(4))) float f32x4;

__device__ inline void gload_lds16(const void* g, void* l) {
  __builtin_amdgcn_global_load_lds(
      (const __attribute__((address_space(1))) void*)g,
      (__attribute__((address_space(3))) void*)l, 16, 0, 0);
}

__device__ inline unsigned short f2bf(float f) {
  __hip_bfloat16 h = __float2bfloat16(f);
  return __builtin_bit_cast(unsigned short, h);
}
__device__ inline float bf2f(unsigned short u) {
  return __bfloat162float(__builtin_bit_cast(__hip_bfloat16, u));
}

// fp8 e4m3 (positive range only: s in [0.28, 3.6], all normal; proven R7-R10)
__device__ inline unsigned f2e4m3(float s) {
  unsigned b = __builtin_bit_cast(unsigned, s);
  return (b + 0x80000u - 0x3C000000u) >> 20;
}
__device__ inline float e4m32f(unsigned u8) {
  return __builtin_bit_cast(float, (u8 << 20) + 0x3C000000u);
}

// ---------------------------------------------------------------------------
// Kernel 1: f32 -> bf16 conversion for v1, v2, W ; zero the nsq accumulators.
// ---------------------------------------------------------------------------
__global__ void convert_kernel(const float* __restrict__ v1,
                               const float* __restrict__ v2,
                               const float* __restrict__ W,
                               unsigned short* __restrict__ v1b,
                               unsigned short* __restrict__ v2b,
                               unsigned short* __restrict__ Wb,
                               float* __restrict__ nsq1,
                               float* __restrict__ nsq2) {
  int idx = blockIdx.x * blockDim.x + threadIdx.x;
  if (idx < NROWS) { nsq1[idx] = 0.f; nsq2[idx] = 0.f; }
  const int TOTV = (NROWS * DDIM) / 4;
  const int TOTW = (DDIM * DDIM) / 4;
  const int total = 2 * TOTV + TOTW;
  const int stride = gridDim.x * blockDim.x;
  for (int i = idx; i < total; i += stride) {
    const float4* src; unsigned short* dst; int j;
    if (i < TOTV)            { src = (const float4*)v1; dst = v1b; j = i; }
    else if (i < 2 * TOTV)   { src = (const float4*)v2; dst = v2b; j = i - TOTV; }
    else                     { src = (const float4*)W;  dst = Wb;  j = i - 2 * TOTV; }
    float4 x = src[j];
    ushort4 o;
    o.x = f2bf(x.x); o.y = f2bf(x.y); o.z = f2bf(x.z); o.w = f2bf(x.w);
    *(ushort4*)&dst[j * 4] = o;
  }
}

// ---------------------------------------------------------------------------
// Kernel 2: projection GEMM  z = elu(v @ W^T + b), bf16 out, + row sum(z^2).
// ---------------------------------------------------------------------------
__global__ __launch_bounds__(256) void proj_kernel(
    const unsigned short* __restrict__ v1b, const unsigned short* __restrict__ v2b,
    const unsigned short* __restrict__ Wb,  const float* __restrict__ bias,
    unsigned short* __restrict__ z1b, unsigned short* __restrict__ z2b,
    float* __restrict__ nsq1, float* __restrict__ nsq2) {
  __shared__ __align__(16) unsigned short As[128 * 32];
  __shared__ __align__(16) unsigned short Bs[128 * 32];
  const int tid = threadIdx.x;
  const int wid = tid >> 6, lane = tid & 63;
  const int wm = wid >> 1, wn = wid & 1;
  const int l15 = lane & 15, l4 = lane >> 4;

  const int zsel = blockIdx.z;
  const unsigned short* Ag = (zsel ? v2b : v1b) + (size_t)blockIdx.y * 128 * DDIM;
  const unsigned short* Bg = Wb + (size_t)blockIdx.x * 128 * DDIM;
  unsigned short* Z = (zsel ? z2b : z1b);
  float* nsq = (zsel ? nsq2 : nsq1);

  f32x4 acc[4][4];
#pragma unroll
  for (int m = 0; m < 4; ++m)
#pragma unroll
    for (int n = 0; n < 4; ++n) acc[m][n] = (f32x4){0.f, 0.f, 0.f, 0.f};

  for (int kt = 0; kt < DDIM; kt += 32) {
#pragma unroll
    for (int i = 0; i < 2; ++i) {
      int off = i * 4096 + tid * 16;
      int row = off >> 6;
      int kb  = off & 63;
      gload_lds16((const char*)(Ag + row * DDIM + kt) + kb,
                  (char*)As + i * 4096 + wid * 1024);
      gload_lds16((const char*)(Bg + row * DDIM + kt) + kb,
                  (char*)Bs + i * 4096 + wid * 1024);
    }
    asm volatile("s_waitcnt vmcnt(0)" ::: "memory");
    __syncthreads();
    short8 av[4], bv[4];
#pragma unroll
    for (int m = 0; m < 4; ++m)
      av[m] = *(const short8*)&As[(wm * 64 + m * 16 + l15) * 32 + l4 * 8];
#pragma unroll
    for (int n = 0; n < 4; ++n)
      bv[n] = *(const short8*)&Bs[(wn * 64 + n * 16 + l15) * 32 + l4 * 8];
#pragma unroll
    for (int m = 0; m < 4; ++m)
#pragma unroll
      for (int n = 0; n < 4; ++n)
        acc[m][n] = __builtin_amdgcn_mfma_f32_16x16x32_bf16(
            av[m], bv[n], acc[m][n], 0, 0, 0);
    __syncthreads();
  }

  const int rowBase = blockIdx.y * 128 + wm * 64;
  const int colBase = blockIdx.x * 128 + wn * 64;
  float bcol[4];
#pragma unroll
  for (int n = 0; n < 4; ++n) bcol[n] = bias[colBase + n * 16 + l15];
#pragma unroll
  for (int m = 0; m < 4; ++m) {
#pragma unroll
    for (int reg = 0; reg < 4; ++reg) {
      int gRow = rowBase + m * 16 + l4 * 4 + reg;
      float rs = 0.f;
#pragma unroll
      for (int n = 0; n < 4; ++n) {
        int gCol = colBase + n * 16 + l15;
        float y = acc[m][n][reg] + bcol[n];
        float zv = (y > 0.f) ? y : expm1f(y);
        unsigned short zb = f2bf(zv);
        Z[(size_t)gRow * DDIM + gCol] = zb;
        float zf = bf2f(zb);
        rs += zf * zf;
      }
      rs += __shfl_xor(rs, 1, 64);
      rs += __shfl_xor(rs, 2, 64);
      rs += __shfl_xor(rs, 4, 64);
      rs += __shfl_xor(rs, 8, 64);
      if (l15 == 0) atomicAdd(&nsq[gRow], rs);
    }
  }
}

// ---------------------------------------------------------------------------
// Kernel 3: pipelined step.  Blocks [0,256): GEMM quarter qG -> sim fp8
// (R7-proven counted-vmcnt pipeline + granule swizzle + LDS-transpose pack).
// Blocks [256,512): wave-coherent 3-stream reduce of quarter qR (written by
// the PREVIOUS launch -> no intra-kernel dependency, no spin).
// ---------------------------------------------------------------------------
__global__ __launch_bounds__(256, 4) void step_kernel(
    const unsigned short* __restrict__ z1b, const unsigned short* __restrict__ z2b,
    const float* __restrict__ nsq1, const float* __restrict__ nsq2,
    const float* __restrict__ pos, const float* __restrict__ neg,
    unsigned char* __restrict__ sim, double* __restrict__ partials,
    int qG, int qR, int pbase) {
  __shared__ __align__(16) char smem[2][16384];
  const int tid = threadIdx.x;

  if (blockIdx.x < 256) {
    // ---------------- GEMM role ----------------
    if (qG < 0) return;
    const int b = blockIdx.x;
    const int by = qG * 8 + (b >> 5), bx = b & 31;

    const int wid = tid >> 6, lane = tid & 63;
    const int wm = wid >> 1, wn = wid & 1;
    const int l15 = lane & 15, l4 = lane >> 4;

    const unsigned short* Ag = z1b + (size_t)by * 128 * DDIM;
    const unsigned short* Bg = z2b + (size_t)bx * 128 * DDIM;

    f32x4 acc[4][4];
#pragma unroll
    for (int m = 0; m < 4; ++m)
#pragma unroll
      for (int n = 0; n < 4; ++n) acc[m][n] = (f32x4){0.f, 0.f, 0.f, 0.f};

#define STAGE(buf, t)                                                          \
    {                                                                          \
      _Pragma("unroll")                                                        \
      for (int i = 0; i < 2; ++i) {                                            \
        int off = i * 4096 + tid * 16;                                         \
        int row = off >> 6;                                                    \
        int gsw = ((off >> 4) & 3) ^ ((row >> 1) & 3);                         \
        gload_lds16((const char*)Ag + row * 1024 + (t) * 64 + gsw * 16,        \
                    smem[buf] + i * 4096 + wid * 1024);                        \
        gload_lds16((const char*)Bg + row * 1024 + (t) * 64 + gsw * 16,        \
                    smem[buf] + 8192 + i * 4096 + wid * 1024);                 \
      }                                                                        \
    }

    STAGE(0, 0);
    STAGE(1, 1);
    const int aswz = (l4 ^ ((l15 >> 1) & 3)) * 8;

#pragma unroll
    for (int t = 0; t < 16; ++t) {
      if (t < 15) asm volatile("s_waitcnt vmcnt(4)" ::: "memory");
      else        asm volatile("s_waitcnt vmcnt(0)" ::: "memory");
      __builtin_amdgcn_s_barrier();
      const unsigned short* As = (const unsigned short*)smem[t & 1];
      const unsigned short* Bs = (const unsigned short*)(smem[t & 1] + 8192);
      short8 av[4], bv[4];
#pragma unroll
      for (int m = 0; m < 4; ++m)
        av[m] = *(const short8*)&As[(wm * 64 + m * 16 + l15) * 32 + aswz];
#pragma unroll
      for (int n = 0; n < 4; ++n)
        bv[n] = *(const short8*)&Bs[(wn * 64 + n * 16 + l15) * 32 + aswz];
#pragma unroll
      for (int m = 0; m < 4; ++m)
#pragma unroll
        for (int n = 0; n < 4; ++n)
          acc[m][n] = __builtin_amdgcn_mfma_f32_16x16x32_bf16(
              av[m], bv[n], acc[m][n], 0, 0, 0);
      __builtin_amdgcn_s_barrier();
      if (t < 14) STAGE(t & 1, t + 2);
    }
#undef STAGE

    const int rowBase = by * 128 + wm * 64;
    const int colBase = bx * 128 + wn * 64;

    float rs2[4], rs1[4][4];
#pragma unroll
    for (int n = 0; n < 4; ++n) rs2[n] = rsqrtf(nsq2[colBase + n * 16 + l15]);
#pragma unroll
    for (int m = 0; m < 4; ++m)
#pragma unroll
      for (int reg = 0; reg < 4; ++reg)
        rs1[m][reg] = rsqrtf(nsq1[rowBase + m * 16 + l4 * 4 + reg]);

    unsigned char* sB = (unsigned char*)smem;
#pragma unroll
    for (int m = 0; m < 4; ++m)
#pragma unroll
      for (int reg = 0; reg < 4; ++reg) {
        int lrow = wm * 64 + m * 16 + l4 * 4 + reg;
#pragma unroll
        for (int n = 0; n < 4; ++n) {
          float s = __expf(acc[m][n][reg] * (rs1[m][reg] * rs2[n]) * INV_TAU);
          sB[lrow * 128 + wn * 64 + n * 16 + l15] = (unsigned char)f2e4m3(s);
        }
      }
    __syncthreads();
    {
      int r = tid >> 1, h = tid & 1;
      const uint4* src = (const uint4*)(sB + r * 128 + h * 64);
      uint4 w0 = src[0], w1 = src[1], w2 = src[2], w3 = src[3];
      uint4* dst = (uint4*)(sim + (size_t)(by * 128 + r) * NROWS + bx * 128 + h * 64);
      dst[0] = w0; dst[1] = w1; dst[2] = w2; dst[3] = w3;
    }
  } else {
    // ---------------- Reduce role (wave-coherent, quarter qR) ----------------
    if (qR < 0) return;
    const int rb = blockIdx.x - 256;              // 0..255
    const int lane = tid & 63;
    const int wv = (rb * 256 + tid) >> 6;         // 0..1023
    const size_t base = (size_t)qR * 4194304 + (size_t)wv * 4096 + (size_t)lane * 4;

    float sumP = 0.f, sumG = 0.f;
#pragma unroll
    for (int g = 0; g < 4; ++g) {
      f32x4 p[4], q[4]; unsigned s[4];
#pragma unroll
      for (int it = 0; it < 4; ++it) {
        size_t off = base + (size_t)(g * 4 + it) * 256;
        p[it] = __builtin_nontemporal_load((const f32x4*)(pos + off));
        q[it] = __builtin_nontemporal_load((const f32x4*)(neg + off));
        s[it] = *(const unsigned*)(sim + off);
      }
#pragma unroll
      for (int it = 0; it < 4; ++it) {
        float s0 = e4m32f((s[it]      ) & 0x7Fu);
        float s1 = e4m32f((s[it] >>  8) & 0x7Fu);
        float s2 = e4m32f((s[it] >> 16) & 0x7Fu);
        float s3 = e4m32f((s[it] >> 24) & 0x7Fu);
        sumP += s0 * p[it][0] + s1 * p[it][1] + s2 * p[it][2] + s3 * p[it][3];
        sumG += s0 * q[it][0] + s1 * q[it][1] + s2 * q[it][2] + s3 * q[it][3];
      }
    }

#pragma unroll
    for (int sft = 1; sft < 64; sft <<= 1) {
      sumP += __shfl_xor(sumP, sft, 64);
      sumG += __shfl_xor(sumG, sft, 64);
    }
    float* red = (float*)smem;
    const int wid = tid >> 6;
    if (lane == 0) { red[wid] = sumP; red[4 + wid] = sumG; }
    __syncthreads();
    if (tid == 0) {
      double tp = (double)red[0] + red[1] + red[2] + red[3];
      double tg = (double)red[4] + red[5] + red[6] + red[7];
      partials[2 * (pbase + rb)]     = tp;
      partials[2 * (pbase + rb) + 1] = tp + tg;   // sumT
    }
  }
}

// ---------------------------------------------------------------------------
// Kernel 4: final reduce of n partial pairs -> -log(sumP / sumT)
// ---------------------------------------------------------------------------
__global__ void finalize_kernel(const double* __restrict__ partials, int n,
                                float* __restrict__ out) {
  __shared__ double sp[256], st[256];
  int t = threadIdx.x;
  double a = 0.0, b = 0.0;
  for (int i = t; i < n; i += 256) {
    a += partials[2 * i];
    b += partials[2 * i + 1];
  }
  sp[t] = a; st[t] = b;
  __syncthreads();
  for (int s = 128; s > 0; s >>= 1) {
    if (t < s) { sp[t] += sp[t + s]; st[t] += st[t + s]; }
    __syncthreads();
  }
  if (t == 0) out[0] = (float)(log(st[0]) - log(sp[0]));
}

// ---------------------------------------------------------------------------
extern "C" void kernel_launch(void* const* d_in, const int* in_sizes, int n_in,
                              void* d_out, int out_size, void* d_ws, size_t ws_size,
                              hipStream_t stream) {
  (void)in_sizes; (void)n_in; (void)out_size; (void)ws_size;
  const float* v1   = (const float*)d_in[0];
  const float* v2   = (const float*)d_in[1];
  const float* pos  = (const float*)d_in[2];
  const float* neg  = (const float*)d_in[3];
  const float* W    = (const float*)d_in[4];
  const float* bias = (const float*)d_in[5];

  char* ws = (char*)d_ws;
  unsigned short* z1b = (unsigned short*)(ws + 0);         // 4 MiB
  unsigned short* z2b = (unsigned short*)(ws + 4194304);   // 4 MiB
  float* nsq1         = (float*)(ws + 8388608);            // 16 KiB
  float* nsq2         = (float*)(ws + 8404992);            // 16 KiB
  double* partials    = (double*)(ws + 8421376);           // 16 KiB (1024 pairs)
  unsigned short* v1b = (unsigned short*)(ws + 8486912);   // 4 MiB
  unsigned short* v2b = (unsigned short*)(ws + 12681216);  // 4 MiB
  unsigned short* Wb  = (unsigned short*)(ws + 16875520);  // 512 KiB
  unsigned char*  sim = (unsigned char*)(ws + 17399808);   // 16 MiB fp8
  float* out = (float*)d_out;

  hipLaunchKernelGGL(convert_kernel, dim3(1024), dim3(256), 0, stream,
                     v1, v2, W, v1b, v2b, Wb, nsq1, nsq2);
  hipLaunchKernelGGL(proj_kernel, dim3(DDIM / 128, NROWS / 128, 2), dim3(256), 0, stream,
                     v1b, v2b, Wb, bias, z1b, z2b, nsq1, nsq2);
  // software pipeline: GEMM quarter q overlaps reduce of quarter q-1
  hipLaunchKernelGGL(step_kernel, dim3(512), dim3(256), 0, stream,
                     z1b, z2b, nsq1, nsq2, pos, neg, sim, partials, 0, -1, 0);
  hipLaunchKernelGGL(step_kernel, dim3(512), dim3(256), 0, stream,
                     z1b, z2b, nsq1, nsq2, pos, neg, sim, partials, 1, 0, 0);
  hipLaunchKernelGGL(step_kernel, dim3(512), dim3(256), 0, stream,
                     z1b, z2b, nsq1, nsq2, pos, neg, sim, partials, 2, 1, 256);
  hipLaunchKernelGGL(step_kernel, dim3(512), dim3(256), 0, stream,
                     z1b, z2b, nsq1, nsq2, pos, neg, sim, partials, 3, 2, 512);
  hipLaunchKernelGGL(step_kernel, dim3(512), dim3(256), 0, stream,
                     z1b, z2b, nsq1, nsq2, pos, neg, sim, partials, -1, 3, 768);
  hipLaunchKernelGGL(finalize_kernel, dim3(1), dim3(256), 0, stream,
                     partials, 1024, out);
}

// Round 13
// 73.067 us; speedup vs baseline: 1.3702x; 1.3609x over previous
//
#include <hip/hip_runtime.h>
#include <hip/hip_bf16.h>
#include <math.h>

#define NROWS 4096
#define DDIM  512
#define INV_TAU 1.25f

typedef __attribute__((ext_vector_type(8))) short short8;
typedef __attribute__((ext_vector_type(4))) float f32x4;

__device__ inline void gload_lds16(const void* g, void* l) {
  __builtin_amdgcn_global_load_lds(
      (const __attribute__((address_space(1))) void*)g,
      (__attribute__((address_space(3))) void*)l, 16, 0, 0);
}

__device__ inline unsigned short f2bf(float f) {
  __hip_bfloat16 h = __float2bfloat16(f);
  return __builtin_bit_cast(unsigned short, h);
}
__device__ inline float bf2f(unsigned short u) {
  return __bfloat162float(__builtin_bit_cast(__hip_bfloat16, u));
}

// fp8 e4m3 (positive range only: s in [0.28, 3.6], all normal; proven R7-R12)
__device__ inline unsigned f2e4m3(float s) {
  unsigned b = __builtin_bit_cast(unsigned, s);
  return (b + 0x80000u - 0x3C000000u) >> 20;
}
__device__ inline float e4m32f(unsigned u8) {
  return __builtin_bit_cast(float, (u8 << 20) + 0x3C000000u);
}

// ---------------------------------------------------------------------------
// Kernel 1: f32 -> bf16 conversion for v1, v2, W ; zero the nsq accumulators.
// ---------------------------------------------------------------------------
__global__ void convert_kernel(const float* __restrict__ v1,
                               const float* __restrict__ v2,
                               const float* __restrict__ W,
                               unsigned short* __restrict__ v1b,
                               unsigned short* __restrict__ v2b,
                               unsigned short* __restrict__ Wb,
                               float* __restrict__ nsq1,
                               float* __restrict__ nsq2) {
  int idx = blockIdx.x * blockDim.x + threadIdx.x;
  if (idx < NROWS) { nsq1[idx] = 0.f; nsq2[idx] = 0.f; }
  const int TOTV = (NROWS * DDIM) / 4;
  const int TOTW = (DDIM * DDIM) / 4;
  const int total = 2 * TOTV + TOTW;
  const int stride = gridDim.x * blockDim.x;
  for (int i = idx; i < total; i += stride) {
    const float4* src; unsigned short* dst; int j;
    if (i < TOTV)            { src = (const float4*)v1; dst = v1b; j = i; }
    else if (i < 2 * TOTV)   { src = (const float4*)v2; dst = v2b; j = i - TOTV; }
    else                     { src = (const float4*)W;  dst = Wb;  j = i - 2 * TOTV; }
    float4 x = src[j];
    ushort4 o;
    o.x = f2bf(x.x); o.y = f2bf(x.y); o.z = f2bf(x.z); o.w = f2bf(x.w);
    *(ushort4*)&dst[j * 4] = o;
  }
}

// ---------------------------------------------------------------------------
// Kernel 2: projection GEMM  z = elu(v @ W^T + b), bf16 out, + row sum(z^2).
// ---------------------------------------------------------------------------
__global__ __launch_bounds__(256) void proj_kernel(
    const unsigned short* __restrict__ v1b, const unsigned short* __restrict__ v2b,
    const unsigned short* __restrict__ Wb,  const float* __restrict__ bias,
    unsigned short* __restrict__ z1b, unsigned short* __restrict__ z2b,
    float* __restrict__ nsq1, float* __restrict__ nsq2) {
  __shared__ __align__(16) unsigned short As[128 * 32];
  __shared__ __align__(16) unsigned short Bs[128 * 32];
  const int tid = threadIdx.x;
  const int wid = tid >> 6, lane = tid & 63;
  const int wm = wid >> 1, wn = wid & 1;
  const int l15 = lane & 15, l4 = lane >> 4;

  const int zsel = blockIdx.z;
  const unsigned short* Ag = (zsel ? v2b : v1b) + (size_t)blockIdx.y * 128 * DDIM;
  const unsigned short* Bg = Wb + (size_t)blockIdx.x * 128 * DDIM;
  unsigned short* Z = (zsel ? z2b : z1b);
  float* nsq = (zsel ? nsq2 : nsq1);

  f32x4 acc[4][4];
#pragma unroll
  for (int m = 0; m < 4; ++m)
#pragma unroll
    for (int n = 0; n < 4; ++n) acc[m][n] = (f32x4){0.f, 0.f, 0.f, 0.f};

  for (int kt = 0; kt < DDIM; kt += 32) {
#pragma unroll
    for (int i = 0; i < 2; ++i) {
      int off = i * 4096 + tid * 16;
      int row = off >> 6;
      int kb  = off & 63;
      gload_lds16((const char*)(Ag + row * DDIM + kt) + kb,
                  (char*)As + i * 4096 + wid * 1024);
      gload_lds16((const char*)(Bg + row * DDIM + kt) + kb,
                  (char*)Bs + i * 4096 + wid * 1024);
    }
    asm volatile("s_waitcnt vmcnt(0)" ::: "memory");
    __syncthreads();
    short8 av[4], bv[4];
#pragma unroll
    for (int m = 0; m < 4; ++m)
      av[m] = *(const short8*)&As[(wm * 64 + m * 16 + l15) * 32 + l4 * 8];
#pragma unroll
    for (int n = 0; n < 4; ++n)
      bv[n] = *(const short8*)&Bs[(wn * 64 + n * 16 + l15) * 32 + l4 * 8];
#pragma unroll
    for (int m = 0; m < 4; ++m)
#pragma unroll
      for (int n = 0; n < 4; ++n)
        acc[m][n] = __builtin_amdgcn_mfma_f32_16x16x32_bf16(
            av[m], bv[n], acc[m][n], 0, 0, 0);
    __syncthreads();
  }

  const int rowBase = blockIdx.y * 128 + wm * 64;
  const int colBase = blockIdx.x * 128 + wn * 64;
  float bcol[4];
#pragma unroll
  for (int n = 0; n < 4; ++n) bcol[n] = bias[colBase + n * 16 + l15];
#pragma unroll
  for (int m = 0; m < 4; ++m) {
#pragma unroll
    for (int reg = 0; reg < 4; ++reg) {
      int gRow = rowBase + m * 16 + l4 * 4 + reg;
      float rs = 0.f;
#pragma unroll
      for (int n = 0; n < 4; ++n) {
        int gCol = colBase + n * 16 + l15;
        float y = acc[m][n][reg] + bcol[n];
        float zv = (y > 0.f) ? y : expm1f(y);
        unsigned short zb = f2bf(zv);
        Z[(size_t)gRow * DDIM + gCol] = zb;
        float zf = bf2f(zb);
        rs += zf * zf;
      }
      rs += __shfl_xor(rs, 1, 64);
      rs += __shfl_xor(rs, 2, 64);
      rs += __shfl_xor(rs, 4, 64);
      rs += __shfl_xor(rs, 8, 64);
      if (l15 == 0) atomicAdd(&nsq[gRow], rs);
    }
  }
}

// ---------------------------------------------------------------------------
// Kernel 3: fused dots, parity-staggered 2-tile chains.
// Each block: tiles (by, bxA) and (by, bxB=bxA+1), 128x128 each.
//   even bid: G(A) S(A) G(B) S(B);  odd bid: G(A) G(B) S(A) S(B).
// 2 blocks/CU co-resident (64KB LDS) -> mixed phases overlap stream (read-
// bound) under GEMM (barrier-bound).  All pieces proven: R4 K-loop, R7 fp8
// convert-to-LDS, R10 wave-coherent stream.  grid: 512  block: 256.
// ---------------------------------------------------------------------------
__global__ __launch_bounds__(256, 2) void dots_kernel(
    const unsigned short* __restrict__ z1b, const unsigned short* __restrict__ z2b,
    const float* __restrict__ nsq1, const float* __restrict__ nsq2,
    const float* __restrict__ pos, const float* __restrict__ neg,
    double* __restrict__ partials) {
  __shared__ __align__(16) char smem[2][16384];         // GEMM staging
  __shared__ __align__(16) unsigned char sChA[16384];   // fp8 s-tile A
  __shared__ __align__(16) unsigned char sChB[16384];   // fp8 s-tile B
  __shared__ float redP[4], redG[4];

  const int tid = threadIdx.x;
  const int wid = tid >> 6, lane = tid & 63;
  const int wm = wid >> 1, wn = wid & 1;
  const int l15 = lane & 15, l4 = lane >> 4;

  const int bid = blockIdx.x;
  const int by = bid >> 4;
  const int bxA = (bid & 15) * 2, bxB = bxA + 1;
  const int blockRow = by * 128;

  const unsigned short* Ag  = z1b + (size_t)by * 128 * DDIM;
  const unsigned short* BgA = z2b + (size_t)bxA * 128 * DDIM;
  const unsigned short* BgB = z2b + (size_t)bxB * 128 * DDIM;

  // hoisted inverse norms
  float rs1v[4][4];
#pragma unroll
  for (int m = 0; m < 4; ++m)
#pragma unroll
    for (int reg = 0; reg < 4; ++reg)
      rs1v[m][reg] = rsqrtf(nsq1[blockRow + wm * 64 + m * 16 + l4 * 4 + reg]);
  float rs2A[4], rs2B[4];
#pragma unroll
  for (int n = 0; n < 4; ++n) {
    rs2A[n] = rsqrtf(nsq2[bxA * 128 + wn * 64 + n * 16 + l15]);
    rs2B[n] = rsqrtf(nsq2[bxB * 128 + wn * 64 + n * 16 + l15]);
  }

  const int aswz = (l4 ^ ((l15 >> 1) & 3)) * 8;
  // stream mapping: wave covers 2 rows/instr, lane-consecutive f32x4
  const int srowS = wid * 2 + (lane >> 5);   // 0..7
  const int scolS = (lane & 31) * 4;         // 0..124

  f32x4 acc[4][4];
  float sumP = 0.f, sumG = 0.f;

#define STAGE(Bg, buf, t)                                                      \
  {                                                                            \
    _Pragma("unroll")                                                          \
    for (int i = 0; i < 2; ++i) {                                              \
      int off = i * 4096 + tid * 16;                                           \
      int row = off >> 6;                                                      \
      int gsw = ((off >> 4) & 3) ^ ((row >> 1) & 3);                           \
      gload_lds16((const char*)Ag + row * 1024 + (t) * 64 + gsw * 16,          \
                  smem[buf] + i * 4096 + wid * 1024);                          \
      gload_lds16((const char*)(Bg) + row * 1024 + (t) * 64 + gsw * 16,        \
                  smem[buf] + 8192 + i * 4096 + wid * 1024);                   \
    }                                                                          \
  }

  // Proven R4 K-loop + R7 fp8 convert; ends with __syncthreads (sCh ready).
#define GEMM_TILE(Bg, sCh, rs2)                                                \
  {                                                                            \
    _Pragma("unroll")                                                          \
    for (int m = 0; m < 4; ++m)                                                \
      _Pragma("unroll")                                                        \
      for (int n = 0; n < 4; ++n) acc[m][n] = (f32x4){0.f, 0.f, 0.f, 0.f};     \
    STAGE(Bg, 0, 0);                                                           \
    STAGE(Bg, 1, 1);                                                           \
    _Pragma("unroll")                                                          \
    for (int t = 0; t < 16; ++t) {                                             \
      if (t < 15) asm volatile("s_waitcnt vmcnt(4)" ::: "memory");             \
      else        asm volatile("s_waitcnt vmcnt(0)" ::: "memory");             \
      __builtin_amdgcn_s_barrier();                                            \
      const unsigned short* As_ = (const unsigned short*)smem[t & 1];          \
      const unsigned short* Bs_ = (const unsigned short*)(smem[t & 1] + 8192); \
      short8 av[4], bv[4];                                                     \
      _Pragma("unroll")                                                        \
      for (int m = 0; m < 4; ++m)                                              \
        av[m] = *(const short8*)&As_[(wm * 64 + m * 16 + l15) * 32 + aswz];    \
      _Pragma("unroll")                                                        \
      for (int n = 0; n < 4; ++n)                                              \
        bv[n] = *(const short8*)&Bs_[(wn * 64 + n * 16 + l15) * 32 + aswz];    \
      _Pragma("unroll")                                                        \
      for (int m = 0; m < 4; ++m)                                              \
        _Pragma("unroll")                                                      \
        for (int n = 0; n < 4; ++n)                                            \
          acc[m][n] = __builtin_amdgcn_mfma_f32_16x16x32_bf16(                 \
              av[m], bv[n], acc[m][n], 0, 0, 0);                               \
      __builtin_amdgcn_s_barrier();                                            \
      if (t < 14) STAGE(Bg, t & 1, t + 2);                                     \
    }                                                                          \
    _Pragma("unroll")                                                          \
    for (int m = 0; m < 4; ++m)                                                \
      _Pragma("unroll")                                                        \
      for (int reg = 0; reg < 4; ++reg) {                                      \
        int lrow = wm * 64 + m * 16 + l4 * 4 + reg;                            \
        _Pragma("unroll")                                                      \
        for (int n = 0; n < 4; ++n) {                                          \
          float s = __expf(acc[m][n][reg] * (rs1v[m][reg] * (rs2)[n]) * INV_TAU);\
          (sCh)[lrow * 128 + wn * 64 + n * 16 + l15] = (unsigned char)f2e4m3(s);\
        }                                                                      \
      }                                                                        \
    __syncthreads();                                                           \
  }

  // Wave-coherent stream of one 128x128 tile: 16 iters, 4-deep load groups.
#define STREAM(sCh, bx)                                                        \
  {                                                                            \
    const float* pb_ = pos + (size_t)(blockRow + srowS) * NROWS + (bx) * 128 + scolS; \
    const float* gb_ = neg + (size_t)(blockRow + srowS) * NROWS + (bx) * 128 + scolS; \
    _Pragma("unroll")                                                          \
    for (int g4 = 0; g4 < 4; ++g4) {                                           \
      f32x4 pv_[4], gv_[4]; unsigned sv_[4];                                   \
      _Pragma("unroll")                                                        \
      for (int it = 0; it < 4; ++it) {                                         \
        int row8 = (g4 * 4 + it) * 8;                                          \
        pv_[it] = *(const f32x4*)(pb_ + (size_t)row8 * NROWS);                 \
        gv_[it] = *(const f32x4*)(gb_ + (size_t)row8 * NROWS);                 \
        sv_[it] = *(const unsigned*)&(sCh)[(srowS + row8) * 128 + scolS];      \
      }                                                                        \
      _Pragma("unroll")                                                        \
      for (int it = 0; it < 4; ++it) {                                         \
        float s0 = e4m32f((sv_[it]      ) & 0x7Fu);                            \
        float s1 = e4m32f((sv_[it] >>  8) & 0x7Fu);                            \
        float s2 = e4m32f((sv_[it] >> 16) & 0x7Fu);                            \
        float s3 = e4m32f((sv_[it] >> 24) & 0x7Fu);                            \
        sumP += s0*pv_[it][0] + s1*pv_[it][1] + s2*pv_[it][2] + s3*pv_[it][3]; \
        sumG += s0*gv_[it][0] + s1*gv_[it][1] + s2*gv_[it][2] + s3*gv_[it][3]; \
      }                                                                        \
    }                                                                          \
    asm volatile("s_waitcnt vmcnt(0)" ::: "memory");                           \
  }

  GEMM_TILE(BgA, sChA, rs2A);
  if (bid & 1) {
    GEMM_TILE(BgB, sChB, rs2B);
    STREAM(sChA, bxA);
    STREAM(sChB, bxB);
  } else {
    STREAM(sChA, bxA);
    GEMM_TILE(BgB, sChB, rs2B);
    STREAM(sChB, bxB);
  }
#undef STAGE
#undef GEMM_TILE
#undef STREAM

#pragma unroll
  for (int sft = 1; sft < 64; sft <<= 1) {
    sumP += __shfl_xor(sumP, sft, 64);
    sumG += __shfl_xor(sumG, sft, 64);
  }
  if (lane == 0) { redP[wid] = sumP; redG[wid] = sumG; }
  __syncthreads();
  if (tid == 0) {
    double tp = (double)redP[0] + redP[1] + redP[2] + redP[3];
    double tg = (double)redG[0] + redG[1] + redG[2] + redG[3];
    partials[2 * bid]     = tp;
    partials[2 * bid + 1] = tp + tg;
  }
}

// ---------------------------------------------------------------------------
// Kernel 4: final reduce of n partial pairs -> -log(sumP / sumT)
// ---------------------------------------------------------------------------
__global__ void finalize_kernel(const double* __restrict__ partials, int n,
                                float* __restrict__ out) {
  __shared__ double sp[256], st[256];
  int t = threadIdx.x;
  double a = 0.0, b = 0.0;
  for (int i = t; i < n; i += 256) {
    a += partials[2 * i];
    b += partials[2 * i + 1];
  }
  sp[t] = a; st[t] = b;
  __syncthreads();
  for (int s = 128; s > 0; s >>= 1) {
    if (t < s) { sp[t] += sp[t + s]; st[t] += st[t + s]; }
    __syncthreads();
  }
  if (t == 0) out[0] = (float)(log(st[0]) - log(sp[0]));
}

// ---------------------------------------------------------------------------
extern "C" void kernel_launch(void* const* d_in, const int* in_sizes, int n_in,
                              void* d_out, int out_size, void* d_ws, size_t ws_size,
                              hipStream_t stream) {
  (void)in_sizes; (void)n_in; (void)out_size; (void)ws_size;
  const float* v1   = (const float*)d_in[0];
  const float* v2   = (const float*)d_in[1];
  const float* pos  = (const float*)d_in[2];
  const float* neg  = (const float*)d_in[3];
  const float* W    = (const float*)d_in[4];
  const float* bias = (const float*)d_in[5];

  char* ws = (char*)d_ws;
  unsigned short* z1b = (unsigned short*)(ws + 0);         // 4 MiB
  unsigned short* z2b = (unsigned short*)(ws + 4194304);   // 4 MiB
  float* nsq1         = (float*)(ws + 8388608);            // 16 KiB
  float* nsq2         = (float*)(ws + 8404992);            // 16 KiB
  double* partials    = (double*)(ws + 8421376);           // 8 KiB (512 pairs)
  unsigned short* v1b = (unsigned short*)(ws + 8486912);   // 4 MiB
  unsigned short* v2b = (unsigned short*)(ws + 12681216);  // 4 MiB
  unsigned short* Wb  = (unsigned short*)(ws + 16875520);  // 512 KiB
  float* out = (float*)d_out;

  hipLaunchKernelGGL(convert_kernel, dim3(1024), dim3(256), 0, stream,
                     v1, v2, W, v1b, v2b, Wb, nsq1, nsq2);
  hipLaunchKernelGGL(proj_kernel, dim3(DDIM / 128, NROWS / 128, 2), dim3(256), 0, stream,
                     v1b, v2b, Wb, bias, z1b, z2b, nsq1, nsq2);
  hipLaunchKernelGGL(dots_kernel, dim3(512), dim3(256), 0, stream,
                     z1b, z2b, nsq1, nsq2, pos, neg, partials);
  hipLaunchKernelGGL(finalize_kernel, dim3(1), dim3(256), 0, stream,
                     partials, 512, out);
}